// Round 3
// baseline (330.716 us; speedup 1.0000x reference)
//
#include <hip/hip_runtime.h>
#include <hip/hip_bf16.h>
#include <math.h>

// GAT encoder, round 12.  13 dispatches:
//  memset | prep_all | scan_ab | scan_c | fill | gemm1 | edge1 |
//  agg1c (chunked segmented-sum) | fix1 | gemm2 | edge2 | agg2c | fix2.
// Round-11 post-mortem: agg1n (per-node quarter-wave gather) regressed 51->55us:
// serial index->gather chains, VGPR 28->36.  Root cause of agg slowness: one
// wave per node (mean degree 13) = tiny serial loops + imbalance.
// Round-12: slots are CSR-sorted by dst -> one wave per 64-slot chunk, indices
// staged to LDS as int4{s,d,w0,w1} (coalesced), inner loop = broadcast
// ds_read_b128 + full-row gather (64 lanes x 8B), 4 gathers in flight, no
// shuffles.  Interior nodes finished in-register (no atomics); boundary nodes
// (~2/chunk) emit plain-store partial records; fixup kernel merges them.

#define NSLOPE 0.2f

using bf16x8 = __attribute__((ext_vector_type(8))) short;
using f32x4  = __attribute__((ext_vector_type(4))) float;
using u16x8  = __attribute__((ext_vector_type(8))) unsigned short;
using u16x4  = __attribute__((ext_vector_type(4))) unsigned short;

__device__ __forceinline__ unsigned short bf16_rne(float f) {
    unsigned u = __float_as_uint(f);
    return (unsigned short)((u + 0x7FFFu + ((u >> 16) & 1u)) >> 16);
}
__device__ __forceinline__ float bf16_to_f(unsigned short h) {
    return __uint_as_float(((unsigned)h) << 16);
}

// -------- merged prep: x->Xhi | split W1 | W2->W2hi | hist --------
__global__ __launch_bounds__(256) void k_prep_all(const float* __restrict__ x,
                                                  const float* __restrict__ W1,
                                                  const float* __restrict__ W2,
                                                  const int* __restrict__ edst,
                                                  unsigned short* __restrict__ Xhi,
                                                  unsigned short* __restrict__ W1hi,
                                                  unsigned short* __restrict__ W1lo,
                                                  unsigned short* __restrict__ W2hi,
                                                  int* __restrict__ deg,
                                                  int BX, int total4, int E) {
    int b = blockIdx.x, t = threadIdx.x;
    if (b < BX) {  // x -> bf16 (hi only): 4 floats / thread
        int id = b * 256 + t;
        if (id >= total4) return;
        float4 v = *(const float4*)&x[(size_t)id * 4];
        unsigned short hi[4];
        hi[0] = bf16_rne(v.x); hi[1] = bf16_rne(v.y);
        hi[2] = bf16_rne(v.z); hi[3] = bf16_rne(v.w);
        *(u16x4*)&Xhi[(size_t)id * 4] = *(u16x4*)hi;
    } else if (b < BX + 64) {  // split+transpose W1 [256,256] -> [n][k]
        int id = (b - BX) * 256 + t;
        int n = id >> 6, kg = id & 63;
        unsigned short hi[4], lo[4];
#pragma unroll
        for (int c = 0; c < 4; ++c) {
            float w = W1[(kg * 4 + c) * 256 + n];
            unsigned short h = bf16_rne(w);
            hi[c] = h;
            lo[c] = bf16_rne(w - bf16_to_f(h));
        }
        *(u16x4*)&W1hi[n * 256 + kg * 4] = *(u16x4*)hi;
        *(u16x4*)&W1lo[n * 256 + kg * 4] = *(u16x4*)lo;
    } else if (b < BX + 128) {  // transpose W2 [256,64] -> [n][k], bf16
        int id = (b - BX - 64) * 256 + t;
        int n = id >> 8, k = id & 255;
        W2hi[n * 256 + k] = bf16_rne(W2[k * 64 + n]);
    } else {  // dst-degree histogram
        int i = (b - BX - 128) * 256 + t;
        if (i < E) atomicAdd(&deg[edst[i]], 1);
    }
}

// -------- fused scan: per-block sums + last-block scans the 256 partials -----
__global__ __launch_bounds__(256) void k_scan_ab(const int* __restrict__ deg,
                                                 int* __restrict__ part,
                                                 int* __restrict__ ticket,
                                                 int* __restrict__ off_n,
                                                 int n, int CH) {
    __shared__ int sd[256];
    __shared__ int lastflag;
    int b = blockIdx.x, t = threadIdx.x;
    int s = b * CH, e = min(n, s + CH);
    int loc = 0;
    for (int i = s + t; i < e; i += 256) loc += deg[i] + 1;  // +1 self-loop
    sd[t] = loc;
    __syncthreads();
    for (int o = 128; o > 0; o >>= 1) {
        if (t < o) sd[t] += sd[t + o];
        __syncthreads();
    }
    if (t == 0) {
        part[b] = sd[0];
        __threadfence();
        int old = atomicAdd(ticket, 1);
        lastflag = (old == (int)gridDim.x - 1);
    }
    __syncthreads();
    if (lastflag) {
        __threadfence();
        int v = ((volatile int*)part)[t];
        sd[t] = v;
        __syncthreads();
        for (int o = 1; o < 256; o <<= 1) {
            int u = (t >= o) ? sd[t - o] : 0;
            __syncthreads();
            sd[t] += u;
            __syncthreads();
        }
        part[t] = sd[t] - v;  // exclusive base per block
        if (t == 255) *off_n = sd[255];
    }
}

__global__ __launch_bounds__(256) void k_scan_c(const int* __restrict__ deg,
                                                const int* __restrict__ part,
                                                int* __restrict__ off,
                                                int* __restrict__ cur,
                                                int* __restrict__ srcl,
                                                int* __restrict__ dstl, int n, int CH) {
    __shared__ int sd[256];
    int b = blockIdx.x, t = threadIdx.x;
    int s = b * CH, e = min(n, s + CH);
    int base = part[b];
    for (int c = s; c < e; c += 256) {
        int i = c + t;
        int v = (i < e) ? (deg[i] + 1) : 0;
        sd[t] = v;
        __syncthreads();
        for (int o = 1; o < 256; o <<= 1) {
            int u = (t >= o) ? sd[t - o] : 0;
            __syncthreads();
            sd[t] += u;
            __syncthreads();
        }
        if (i < e) {
            int ex = base + sd[t] - v;
            off[i] = ex;
            cur[i] = ex + 1;   // slot ex holds the self-loop
            srcl[ex] = i;
            dstl[ex] = i;
        }
        base += sd[255];
        __syncthreads();
    }
}

__global__ void k_fill(const int* __restrict__ src, const int* __restrict__ dst,
                       int* cur, int* __restrict__ srcl, int* __restrict__ dstl, int E) {
    int i = blockIdx.x * blockDim.x + threadIdx.x;
    if (i >= E) return;
    int s = src[i], d = dst[i];
    int p = atomicAdd(&cur[d], 1);
    srcl[p] = s;
    dstl[p] = d;
}

// -- GEMM1: 2-term xhi x (W1hi+W1lo), 128x128 tile (blockIdx.y=head), alpha1 fused
#define G1S 40  // LDS row stride in ushort (32 k + 8 pad)
__global__ __launch_bounds__(256) void k_gemm1(const unsigned short* __restrict__ Xhi,
                                               const unsigned short* __restrict__ Whi,
                                               const unsigned short* __restrict__ Wlo,
                                               const float* __restrict__ a1s,
                                               const float* __restrict__ a1d,
                                               unsigned short* __restrict__ h1b,
                                               float* __restrict__ as_,
                                               float* __restrict__ ad_, int M) {
    __shared__ unsigned short sAh[128 * G1S];
    __shared__ unsigned short sBh[128 * G1S], sBl[128 * G1S];
    __shared__ float salS[128][2], salD[128][2];
    int t = threadIdx.x;
    int lane = t & 63, wave = t >> 6;
    int q = lane >> 4, m = lane & 15;
    int row0 = blockIdx.x * 128;
    int head = blockIdx.y;
    int col0 = head * 128;
    int rbase = (wave & 1) * 64, cbase = (wave >> 1) * 64;
    f32x4 acc[4][4];
#pragma unroll
    for (int i = 0; i < 4; ++i)
#pragma unroll
        for (int j = 0; j < 4; ++j) acc[i][j] = (f32x4){0.f, 0.f, 0.f, 0.f};

    for (int kc = 0; kc < 256; kc += 32) {
#pragma unroll
        for (int i2 = 0; i2 < 2; ++i2) {
            int slot = t + i2 * 256;
            int r = slot >> 2, kg = slot & 3;
            int row = row0 + r;
            u16x8 vh = {0, 0, 0, 0, 0, 0, 0, 0};
            if (row < M) vh = *(const u16x8*)&Xhi[(size_t)row * 256 + kc + kg * 8];
            *(u16x8*)&sAh[r * G1S + kg * 8] = vh;
        }
#pragma unroll
        for (int i2 = 0; i2 < 2; ++i2) {
            int slot = t + i2 * 256;
            int n = slot >> 2, kg = slot & 3;
            *(u16x8*)&sBh[n * G1S + kg * 8] =
                *(const u16x8*)&Whi[(size_t)(col0 + n) * 256 + kc + kg * 8];
            *(u16x8*)&sBl[n * G1S + kg * 8] =
                *(const u16x8*)&Wlo[(size_t)(col0 + n) * 256 + kc + kg * 8];
        }
        __syncthreads();
        bf16x8 ah[4], bh[4], bl[4];
#pragma unroll
        for (int i = 0; i < 4; ++i)
            ah[i] = *(bf16x8*)&sAh[(rbase + i * 16 + m) * G1S + q * 8];
#pragma unroll
        for (int j = 0; j < 4; ++j) {
            int r = (cbase + j * 16 + m) * G1S + q * 8;
            bh[j] = *(bf16x8*)&sBh[r];
            bl[j] = *(bf16x8*)&sBl[r];
        }
#pragma unroll
        for (int i = 0; i < 4; ++i)
#pragma unroll
            for (int j = 0; j < 4; ++j) {
                acc[i][j] = __builtin_amdgcn_mfma_f32_16x16x32_bf16(ah[i], bl[j], acc[i][j], 0, 0, 0);
                acc[i][j] = __builtin_amdgcn_mfma_f32_16x16x32_bf16(ah[i], bh[j], acc[i][j], 0, 0, 0);
            }
        __syncthreads();
    }
    float sv[4], dv[4];
#pragma unroll
    for (int j = 0; j < 4; ++j) {
        sv[j] = a1s[head * 128 + cbase + j * 16 + m];
        dv[j] = a1d[head * 128 + cbase + j * 16 + m];
    }
#pragma unroll
    for (int i = 0; i < 4; ++i) {
#pragma unroll
        for (int r = 0; r < 4; ++r) {
            int rl = rbase + i * 16 + q * 4 + r;
            int row = row0 + rl;
            float ps = acc[i][0][r] * sv[0] + acc[i][1][r] * sv[1]
                     + acc[i][2][r] * sv[2] + acc[i][3][r] * sv[3];
            float pd = acc[i][0][r] * dv[0] + acc[i][1][r] * dv[1]
                     + acc[i][2][r] * dv[2] + acc[i][3][r] * dv[3];
#pragma unroll
            for (int mask = 1; mask < 16; mask <<= 1) {
                ps += __shfl_xor(ps, mask, 64);
                pd += __shfl_xor(pd, mask, 64);
            }
            if (m == 0) {
                salS[rl][cbase >> 6] = ps;
                salD[rl][cbase >> 6] = pd;
            }
            if (row < M) {
#pragma unroll
                for (int j = 0; j < 4; ++j)
                    h1b[(size_t)row * 256 + col0 + cbase + j * 16 + m] = bf16_rne(acc[i][j][r]);
            }
        }
    }
    __syncthreads();
    if (t < 128) {
        int row = row0 + t;
        if (row < M) {
            as_[row * 2 + head] = salS[t][0] + salS[t][1];
            ad_[row * 2 + head] = salD[t][0] + salD[t][1];
        }
    }
}

// ------- layer-1 per-slot weight precompute (edge-parallel, coalesced) -------
__global__ __launch_bounds__(256) void k_edge1(const int* __restrict__ srcl,
                                               const int* __restrict__ dstl,
                                               const float* __restrict__ as,
                                               const float* __restrict__ ad,
                                               float2* __restrict__ w01, int T) {
    int p = blockIdx.x * blockDim.x + threadIdx.x;
    if (p >= T) return;
    int s = srcl[p], d = dstl[p];
    float2 av = *(const float2*)&as[s * 2];
    float2 dv = *(const float2*)&ad[d * 2];
    float l0 = av.x + dv.x; l0 = l0 >= 0.f ? l0 : NSLOPE * l0;
    float l1 = av.y + dv.y; l1 = l1 >= 0.f ? l1 : NSLOPE * l1;
    w01[p] = make_float2(__expf(l0), __expf(l1));
}

// ------- layer-1 chunked aggregate: wave per 64 slots, CSR-segmented --------
// Interior nodes finished in-register; boundary nodes -> partial records.
__global__ __launch_bounds__(256) void k_agg1c(const unsigned short* __restrict__ h1b,
                                               const int* __restrict__ srcl,
                                               const int* __restrict__ dstl,
                                               const float2* __restrict__ w01,
                                               const int* __restrict__ off,
                                               const float* __restrict__ b1,
                                               unsigned short* __restrict__ helu_b,
                                               int* __restrict__ pnode,
                                               float* __restrict__ psw,   // [R][2]
                                               float* __restrict__ pacc,  // [R][256]
                                               int N, int T) {
    __shared__ int4 sl[256];
    int t = threadIdx.x;
    int p = blockIdx.x * 256 + t;
    int4 pk;
    if (p < T) {
        float2 w = w01[p];
        pk = make_int4(srcl[p], dstl[p], __float_as_int(w.x), __float_as_int(w.y));
    } else {
        pk = make_int4(0, N, 0, 0);  // sentinel node id = N, w = 0
    }
    sl[t] = pk;
    __syncthreads();
    int wave = t >> 6, lane = t & 63;
    int p0 = blockIdx.x * 256 + wave * 64;
    if (p0 >= T) return;
    int chunkid = p0 >> 6;
    int cntr = min(64, T - p0);
    const int4* slw = &sl[wave * 64];
    float4 bv = *(const float4*)&b1[lane * 4];
    float a0 = 0.f, a1 = 0.f, a2 = 0.f, a3 = 0.f, sumw = 0.f;
    int4 r0i = slw[0];
    int dcur = r0i.y;
    bool started_in = (off[dcur] == p0);
    int nrec = 0;

#define FLUSH1(COMPLETE)                                                      \
    {                                                                         \
        if (COMPLETE) {                                                       \
            float inv = 1.0f / sumw;                                          \
            float v0 = a0 * inv + bv.x; v0 = v0 > 0.f ? v0 : expm1f(v0);      \
            float v1 = a1 * inv + bv.y; v1 = v1 > 0.f ? v1 : expm1f(v1);      \
            float v2 = a2 * inv + bv.z; v2 = v2 > 0.f ? v2 : expm1f(v2);      \
            float v3 = a3 * inv + bv.w; v3 = v3 > 0.f ? v3 : expm1f(v3);      \
            unsigned short o_[4];                                             \
            o_[0] = bf16_rne(v0); o_[1] = bf16_rne(v1);                       \
            o_[2] = bf16_rne(v2); o_[3] = bf16_rne(v3);                       \
            *(u16x4*)&helu_b[(size_t)dcur * 256 + lane * 4] = *(u16x4*)o_;    \
        } else {                                                              \
            int rec = chunkid * 2 + nrec;                                     \
            nrec++;                                                           \
            if (lane == 0) { pnode[rec] = dcur; psw[rec * 2] = sumw; }        \
            if (lane == 32) psw[rec * 2 + 1] = sumw;                          \
            *(float4*)&pacc[(size_t)rec * 256 + lane * 4] =                   \
                make_float4(a0, a1, a2, a3);                                  \
        }                                                                     \
    }

#define PROC1(Q, H)                                                           \
    {                                                                         \
        if ((Q).y != dcur) {                                                  \
            FLUSH1(started_in);                                               \
            dcur = (Q).y; started_in = true;                                  \
            a0 = a1 = a2 = a3 = 0.f; sumw = 0.f;                              \
        }                                                                     \
        float w_ = __int_as_float(lane < 32 ? (Q).z : (Q).w);                 \
        sumw += w_;                                                           \
        a0 += w_ * bf16_to_f((unsigned short)(H)[0]);                         \
        a1 += w_ * bf16_to_f((unsigned short)(H)[1]);                         \
        a2 += w_ * bf16_to_f((unsigned short)(H)[2]);                         \
        a3 += w_ * bf16_to_f((unsigned short)(H)[3]);                         \
    }

    for (int kk = 0; kk < 64; kk += 4) {
        int4 q0 = slw[kk], q1 = slw[kk + 1], q2 = slw[kk + 2], q3 = slw[kk + 3];
        u16x4 h0 = *(const u16x4*)&h1b[(size_t)q0.x * 256 + lane * 4];
        u16x4 h1 = *(const u16x4*)&h1b[(size_t)q1.x * 256 + lane * 4];
        u16x4 h2 = *(const u16x4*)&h1b[(size_t)q2.x * 256 + lane * 4];
        u16x4 h3 = *(const u16x4*)&h1b[(size_t)q3.x * 256 + lane * 4];
        PROC1(q0, h0); PROC1(q1, h1); PROC1(q2, h2); PROC1(q3, h3);
    }
    if (dcur < N) {
        bool ends_in = (off[dcur + 1] == p0 + cntr);
        bool comp = started_in && ends_in;
        FLUSH1(comp);
    }
    if (lane == 0) {
        for (int r = nrec; r < 2; ++r) pnode[chunkid * 2 + r] = -1;
    }
#undef PROC1
#undef FLUSH1
}

// ------- layer-1 fixup: merge partial records of split nodes ---------------
__global__ __launch_bounds__(256) void k_fix1(const int* __restrict__ off,
                                              const int* __restrict__ pnode,
                                              const float* __restrict__ psw,
                                              const float* __restrict__ pacc,
                                              const float* __restrict__ b1,
                                              unsigned short* __restrict__ helu_b,
                                              int N) {
    int wid = (blockIdx.x * 256 + threadIdx.x) >> 6;
    int lane = threadIdx.x & 63;
    int nend = min(wid * 4 + 4, N);
    for (int n = wid * 4; n < nend; ++n) {
        int o0 = off[n], o1 = off[n + 1];
        int c0 = o0 >> 6, c1 = (o1 - 1) >> 6;
        if (c0 == c1) continue;  // finished by a single chunk wave
        float a0 = 0.f, a1 = 0.f, a2 = 0.f, a3 = 0.f, sw = 0.f;
        for (int c = c0; c <= c1; ++c) {
#pragma unroll
            for (int rr = 0; rr < 2; ++rr) {
                int rec = c * 2 + rr;
                if (pnode[rec] == n) {
                    sw += psw[rec * 2 + (lane < 32 ? 0 : 1)];
                    float4 pa = *(const float4*)&pacc[(size_t)rec * 256 + lane * 4];
                    a0 += pa.x; a1 += pa.y; a2 += pa.z; a3 += pa.w;
                }
            }
        }
        float inv = 1.0f / sw;
        float4 bv = *(const float4*)&b1[lane * 4];
        float v0 = a0 * inv + bv.x; v0 = v0 > 0.f ? v0 : expm1f(v0);
        float v1 = a1 * inv + bv.y; v1 = v1 > 0.f ? v1 : expm1f(v1);
        float v2 = a2 * inv + bv.z; v2 = v2 > 0.f ? v2 : expm1f(v2);
        float v3 = a3 * inv + bv.w; v3 = v3 > 0.f ? v3 : expm1f(v3);
        unsigned short o_[4];
        o_[0] = bf16_rne(v0); o_[1] = bf16_rne(v1);
        o_[2] = bf16_rne(v2); o_[3] = bf16_rne(v3);
        *(u16x4*)&helu_b[(size_t)n * 256 + lane * 4] = *(u16x4*)o_;
    }
}

// ---------------- GEMM2: 1-term bf16-A x bf16-B MFMA, alpha2 fused ----------
__global__ __launch_bounds__(256) void k_gemm2(const unsigned short* __restrict__ hb,
                                               const unsigned short* __restrict__ Whi,
                                               const float* __restrict__ a2s,
                                               const float* __restrict__ a2d,
                                               unsigned short* __restrict__ h2b,
                                               float* __restrict__ as_,
                                               float* __restrict__ ad_, int M) {
    __shared__ unsigned short sA[128 * G1S];
    __shared__ unsigned short sBh[64 * G1S];
    int t = threadIdx.x;
    int lane = t & 63, wave = t >> 6;
    int q = lane >> 4, m = lane & 15;
    int row0 = blockIdx.x * 128;
    int rbase = wave * 32;
    f32x4 acc[2][4];
#pragma unroll
    for (int i = 0; i < 2; ++i)
#pragma unroll
        for (int j = 0; j < 4; ++j) acc[i][j] = (f32x4){0.f, 0.f, 0.f, 0.f};

    for (int kc = 0; kc < 256; kc += 32) {
#pragma unroll
        for (int i = 0; i < 2; ++i) {
            int slot = t + i * 256;
            int r = slot >> 2, kg = slot & 3;
            int row = row0 + r;
            u16x8 v = {0, 0, 0, 0, 0, 0, 0, 0};
            if (row < M) v = *(const u16x8*)&hb[(size_t)row * 256 + kc + kg * 8];
            *(u16x8*)&sA[r * G1S + kg * 8] = v;
        }
        {
            int n = t >> 2, kg = t & 3;
            *(u16x8*)&sBh[n * G1S + kg * 8] =
                *(const u16x8*)&Whi[(size_t)n * 256 + kc + kg * 8];
        }
        __syncthreads();
        bf16x8 a[2], bh[4];
#pragma unroll
        for (int i = 0; i < 2; ++i)
            a[i] = *(bf16x8*)&sA[(rbase + i * 16 + m) * G1S + q * 8];
#pragma unroll
        for (int j = 0; j < 4; ++j)
            bh[j] = *(bf16x8*)&sBh[(j * 16 + m) * G1S + q * 8];
#pragma unroll
        for (int i = 0; i < 2; ++i)
#pragma unroll
            for (int j = 0; j < 4; ++j)
                acc[i][j] = __builtin_amdgcn_mfma_f32_16x16x32_bf16(a[i], bh[j], acc[i][j], 0, 0, 0);
        __syncthreads();
    }
    float sv[4], dv[4];
#pragma unroll
    for (int j = 0; j < 4; ++j) {
        sv[j] = a2s[j * 16 + m];
        dv[j] = a2d[j * 16 + m];
    }
#pragma unroll
    for (int i = 0; i < 2; ++i) {
#pragma unroll
        for (int r = 0; r < 4; ++r) {
            int row = row0 + rbase + i * 16 + q * 4 + r;
            float ps = acc[i][0][r] * sv[0] + acc[i][1][r] * sv[1]
                     + acc[i][2][r] * sv[2] + acc[i][3][r] * sv[3];
            float pd = acc[i][0][r] * dv[0] + acc[i][1][r] * dv[1]
                     + acc[i][2][r] * dv[2] + acc[i][3][r] * dv[3];
#pragma unroll
            for (int mask = 1; mask < 16; mask <<= 1) {
                ps += __shfl_xor(ps, mask, 64);
                pd += __shfl_xor(pd, mask, 64);
            }
            if (row < M) {
#pragma unroll
                for (int j = 0; j < 4; ++j)
                    h2b[(size_t)row * 64 + j * 16 + m] = bf16_rne(acc[i][j][r]);
                if (m == 0) { as_[row] = ps; ad_[row] = pd; }
            }
        }
    }
}

// ------- layer-2 per-slot weight precompute -------
__global__ __launch_bounds__(256) void k_edge2(const int* __restrict__ srcl,
                                               const int* __restrict__ dstl,
                                               const float* __restrict__ as,
                                               const float* __restrict__ ad,
                                               float* __restrict__ w2l, int T) {
    int p = blockIdx.x * blockDim.x + threadIdx.x;
    if (p >= T) return;
    int s = srcl[p], d = dstl[p];
    float l = as[s] + ad[d];
    l = l >= 0.f ? l : NSLOPE * l;
    w2l[p] = __expf(l);
}

// ------- layer-2 chunked aggregate (64 ch, f32 out) -------------------------
__global__ __launch_bounds__(256) void k_agg2c(const unsigned short* __restrict__ h2b,
                                               const int* __restrict__ srcl,
                                               const int* __restrict__ dstl,
                                               const float* __restrict__ w2l,
                                               const int* __restrict__ off,
                                               const float* __restrict__ b2,
                                               float* __restrict__ out,
                                               int* __restrict__ pnode,
                                               float* __restrict__ psw,   // [R]
                                               float* __restrict__ pacc,  // [R][64]
                                               int N, int T) {
    __shared__ int4 sl[256];
    int t = threadIdx.x;
    int p = blockIdx.x * 256 + t;
    int4 pk;
    if (p < T) {
        pk = make_int4(srcl[p], dstl[p], __float_as_int(w2l[p]), 0);
    } else {
        pk = make_int4(0, N, 0, 0);
    }
    sl[t] = pk;
    __syncthreads();
    int wave = t >> 6, lane = t & 63;
    int p0 = blockIdx.x * 256 + wave * 64;
    if (p0 >= T) return;
    int chunkid = p0 >> 6;
    int cntr = min(64, T - p0);
    const int4* slw = &sl[wave * 64];
    float bb = b2[lane];
    float a0 = 0.f, sumw = 0.f;
    int4 r0i = slw[0];
    int dcur = r0i.y;
    bool started_in = (off[dcur] == p0);
    int nrec = 0;

#define FLUSH2(COMPLETE)                                                      \
    {                                                                         \
        if (COMPLETE) {                                                       \
            out[(size_t)dcur * 64 + lane] = a0 / sumw + bb;                   \
        } else {                                                              \
            int rec = chunkid * 2 + nrec;                                     \
            nrec++;                                                           \
            if (lane == 0) { pnode[rec] = dcur; psw[rec] = sumw; }            \
            pacc[(size_t)rec * 64 + lane] = a0;                               \
        }                                                                     \
    }

#define PROC2(Q, HV)                                                          \
    {                                                                         \
        if ((Q).y != dcur) {                                                  \
            FLUSH2(started_in);                                               \
            dcur = (Q).y; started_in = true;                                  \
            a0 = 0.f; sumw = 0.f;                                             \
        }                                                                     \
        float w_ = __int_as_float((Q).z);                                     \
        sumw += w_;                                                           \
        a0 += w_ * bf16_to_f(HV);                                             \
    }

    for (int kk = 0; kk < 64; kk += 4) {
        int4 q0 = slw[kk], q1 = slw[kk + 1], q2 = slw[kk + 2], q3 = slw[kk + 3];
        unsigned short h0 = h2b[(size_t)q0.x * 64 + lane];
        unsigned short h1 = h2b[(size_t)q1.x * 64 + lane];
        unsigned short h2 = h2b[(size_t)q2.x * 64 + lane];
        unsigned short h3 = h2b[(size_t)q3.x * 64 + lane];
        PROC2(q0, h0); PROC2(q1, h1); PROC2(q2, h2); PROC2(q3, h3);
    }
    if (dcur < N) {
        bool ends_in = (off[dcur + 1] == p0 + cntr);
        bool comp = started_in && ends_in;
        FLUSH2(comp);
    }
    if (lane == 0) {
        for (int r = nrec; r < 2; ++r) pnode[chunkid * 2 + r] = -1;
    }
#undef PROC2
#undef FLUSH2
}

// ------- layer-2 fixup ------------------------------------------------------
__global__ __launch_bounds__(256) void k_fix2(const int* __restrict__ off,
                                              const int* __restrict__ pnode,
                                              const float* __restrict__ psw,
                                              const float* __restrict__ pacc,
                                              const float* __restrict__ b2,
                                              float* __restrict__ out, int N) {
    int wid = (blockIdx.x * 256 + threadIdx.x) >> 6;
    int lane = threadIdx.x & 63;
    int nend = min(wid * 4 + 4, N);
    for (int n = wid * 4; n < nend; ++n) {
        int o0 = off[n], o1 = off[n + 1];
        int c0 = o0 >> 6, c1 = (o1 - 1) >> 6;
        if (c0 == c1) continue;
        float a0 = 0.f, sw = 0.f;
        for (int c = c0; c <= c1; ++c) {
#pragma unroll
            for (int rr = 0; rr < 2; ++rr) {
                int rec = c * 2 + rr;
                if (pnode[rec] == n) {
                    sw += psw[rec];
                    a0 += pacc[(size_t)rec * 64 + lane];
                }
            }
        }
        out[(size_t)n * 64 + lane] = a0 / sw + b2[lane];
    }
}

// ---------------- launch ----------------
extern "C" void kernel_launch(void* const* d_in, const int* in_sizes, int n_in,
                              void* d_out, int out_size, void* d_ws, size_t ws_size,
                              hipStream_t stream) {
    if (n_in < 10) return;
    const float* x   = (const float*)d_in[0];
    const int*   ei  = (const int*)d_in[1];
    const float* W1  = (const float*)d_in[2];
    const float* a1s = (const float*)d_in[3];
    const float* a1d = (const float*)d_in[4];
    const float* b1  = (const float*)d_in[5];
    const float* W2  = (const float*)d_in[6];
    const float* a2s = (const float*)d_in[7];
    const float* a2d = (const float*)d_in[8];
    const float* b2  = (const float*)d_in[9];
    float* out = (float*)d_out;

    const int N = in_sizes[0] / 256;
    const int E = in_sizes[1] / 2;
    const int T = E + N;
    const int* esrc = ei;
    const int* edst = ei + E;

    char* ws = (char*)d_ws;
    size_t o = 0;
    auto alloc = [&](size_t bytes) -> void* {
        void* p = ws + o;
        o = (o + bytes + 255) & ~(size_t)255;
        return p;
    };
    // Xhi (dead after gemm1) aliased with helu_b (written by agg1c/fix1)
    size_t szX = (size_t)N * 256 * 2;
    char* regionA = (char*)alloc(szX);
    unsigned short* Xhi    = (unsigned short*)regionA;
    unsigned short* helu_b = (unsigned short*)regionA;

    unsigned short* h1b  = (unsigned short*)alloc((size_t)N * 256 * 2);
    unsigned short* W1hi = (unsigned short*)alloc(256 * 256 * 2);
    unsigned short* W1lo = (unsigned short*)alloc(256 * 256 * 2);
    unsigned short* W2hi = (unsigned short*)alloc(64 * 256 * 2);
    unsigned short* h2b  = (unsigned short*)alloc((size_t)N * 64 * 2);
    float* al1s = (float*)alloc((size_t)N * 2 * 4);
    float* al1d = (float*)alloc((size_t)N * 2 * 4);
    float* al2s = (float*)alloc((size_t)N * 4);
    float* al2d = (float*)alloc((size_t)N * 4);
    int* deg  = (int*)alloc((size_t)(N + 64) * 4);  // deg[N] + ticket counter
    int* ticket = deg + N;
    int* off  = (int*)alloc((size_t)(N + 1) * 4);
    int* cur  = (int*)alloc((size_t)N * 4);
    int* part = (int*)alloc(256 * 4);
    int* srcl = (int*)alloc((size_t)T * 4);
    int* dstl = (int*)alloc((size_t)T * 4);
    float2* w01 = (float2*)alloc((size_t)T * 8);
    float* w2l  = (float*)alloc((size_t)T * 4);
    const int NCH = (T + 63) / 64;   // 64-slot chunks
    const int R = 2 * NCH;           // partial records (2 per chunk)
    int*   pnode1 = (int*)alloc((size_t)R * 4);
    float* psw1   = (float*)alloc((size_t)R * 2 * 4);
    float* pacc1  = (float*)alloc((size_t)R * 256 * 4);
    int*   pnode2 = (int*)alloc((size_t)R * 4);
    float* psw2   = (float*)alloc((size_t)R * 4);
    float* pacc2  = (float*)alloc((size_t)R * 64 * 4);
    if (o > ws_size) return;

    const int CH = (N + 255) / 256;
    const int total4 = N * 64;
    const int BX = (total4 + 255) / 256;
    const int BH = (E + 255) / 256;
    const int BT = (T + 255) / 256;
    const int BFIX = (N + 15) / 16;  // 4 waves x 4 nodes per block

    hipMemsetAsync(deg, 0, (size_t)(N + 64) * 4, stream);
    k_prep_all<<<BX + 128 + BH, 256, 0, stream>>>(x, W1, W2, edst, Xhi,
                                                  W1hi, W1lo, W2hi, deg,
                                                  BX, total4, E);
    k_scan_ab<<<256, 256, 0, stream>>>(deg, part, ticket, &off[N], N, CH);
    k_scan_c<<<256, 256, 0, stream>>>(deg, part, off, cur, srcl, dstl, N, CH);
    k_fill<<<(E + 255) / 256, 256, 0, stream>>>(esrc, edst, cur, srcl, dstl, E);

    // layer 1
    dim3 g1((N + 127) / 128, 2);
    k_gemm1<<<g1, 256, 0, stream>>>(Xhi, W1hi, W1lo, a1s, a1d, h1b, al1s, al1d, N);
    k_edge1<<<BT, 256, 0, stream>>>(srcl, dstl, al1s, al1d, w01, T);
    k_agg1c<<<BT, 256, 0, stream>>>(h1b, srcl, dstl, w01, off, b1, helu_b,
                                    pnode1, psw1, pacc1, N, T);
    k_fix1<<<BFIX, 256, 0, stream>>>(off, pnode1, psw1, pacc1, b1, helu_b, N);

    // layer 2
    k_gemm2<<<(N + 127) / 128, 256, 0, stream>>>(helu_b, W2hi, a2s, a2d,
                                                 h2b, al2s, al2d, N);
    k_edge2<<<BT, 256, 0, stream>>>(srcl, dstl, al2s, al2d, w2l, T);
    k_agg2c<<<BT, 256, 0, stream>>>(h2b, srcl, dstl, w2l, off, b2, out,
                                    pnode2, psw2, pacc2, N, T);
    k_fix2<<<BFIX, 256, 0, stream>>>(off, pnode2, psw2, pacc2, b2, out, N);
}

// Round 4
// 302.708 us; speedup vs baseline: 1.0925x; 1.0925x over previous
//
#include <hip/hip_runtime.h>
#include <hip/hip_bf16.h>
#include <math.h>

// GAT encoder, round 13.  11 dispatches:
//  memset | prep_all | scan_ab | scan_c | fill | gemm1 | edge1 | agg1 |
//  gemm2 | edge2 | agg2.
// Round-12 post-mortem: both agg restructures (r10 quarter-wave, r12 chunked
// segmented) lost to the round-9 pair-shuffle gather (50.9us).  Keep round-9
// agg loops EXACTLY; only move the per-edge weight computation (2x expf +
// leaky + random as[s] gather in the critical path) into an edge-parallel
// coalesced precompute (edge1/edge2).  Weight bits identical; agg summation
// order identical to round 9 -> absmax unchanged (0.0039 @ 0.01625).

#define NSLOPE 0.2f

using bf16x8 = __attribute__((ext_vector_type(8))) short;
using f32x4  = __attribute__((ext_vector_type(4))) float;
using u16x8  = __attribute__((ext_vector_type(8))) unsigned short;
using u16x4  = __attribute__((ext_vector_type(4))) unsigned short;

__device__ __forceinline__ unsigned short bf16_rne(float f) {
    unsigned u = __float_as_uint(f);
    return (unsigned short)((u + 0x7FFFu + ((u >> 16) & 1u)) >> 16);
}
__device__ __forceinline__ float bf16_to_f(unsigned short h) {
    return __uint_as_float(((unsigned)h) << 16);
}

// -------- merged prep: x->Xhi | split W1 | W2->W2hi | hist --------
__global__ __launch_bounds__(256) void k_prep_all(const float* __restrict__ x,
                                                  const float* __restrict__ W1,
                                                  const float* __restrict__ W2,
                                                  const int* __restrict__ edst,
                                                  unsigned short* __restrict__ Xhi,
                                                  unsigned short* __restrict__ W1hi,
                                                  unsigned short* __restrict__ W1lo,
                                                  unsigned short* __restrict__ W2hi,
                                                  int* __restrict__ deg,
                                                  int BX, int total4, int E) {
    int b = blockIdx.x, t = threadIdx.x;
    if (b < BX) {  // x -> bf16 (hi only): 4 floats / thread
        int id = b * 256 + t;
        if (id >= total4) return;
        float4 v = *(const float4*)&x[(size_t)id * 4];
        unsigned short hi[4];
        hi[0] = bf16_rne(v.x); hi[1] = bf16_rne(v.y);
        hi[2] = bf16_rne(v.z); hi[3] = bf16_rne(v.w);
        *(u16x4*)&Xhi[(size_t)id * 4] = *(u16x4*)hi;
    } else if (b < BX + 64) {  // split+transpose W1 [256,256] -> [n][k]
        int id = (b - BX) * 256 + t;
        int n = id >> 6, kg = id & 63;
        unsigned short hi[4], lo[4];
#pragma unroll
        for (int c = 0; c < 4; ++c) {
            float w = W1[(kg * 4 + c) * 256 + n];
            unsigned short h = bf16_rne(w);
            hi[c] = h;
            lo[c] = bf16_rne(w - bf16_to_f(h));
        }
        *(u16x4*)&W1hi[n * 256 + kg * 4] = *(u16x4*)hi;
        *(u16x4*)&W1lo[n * 256 + kg * 4] = *(u16x4*)lo;
    } else if (b < BX + 128) {  // transpose W2 [256,64] -> [n][k], bf16
        int id = (b - BX - 64) * 256 + t;
        int n = id >> 8, k = id & 255;
        W2hi[n * 256 + k] = bf16_rne(W2[k * 64 + n]);
    } else {  // dst-degree histogram
        int i = (b - BX - 128) * 256 + t;
        if (i < E) atomicAdd(&deg[edst[i]], 1);
    }
}

// -------- fused scan: per-block sums + last-block scans the 256 partials -----
__global__ __launch_bounds__(256) void k_scan_ab(const int* __restrict__ deg,
                                                 int* __restrict__ part,
                                                 int* __restrict__ ticket,
                                                 int* __restrict__ off_n,
                                                 int n, int CH) {
    __shared__ int sd[256];
    __shared__ int lastflag;
    int b = blockIdx.x, t = threadIdx.x;
    int s = b * CH, e = min(n, s + CH);
    int loc = 0;
    for (int i = s + t; i < e; i += 256) loc += deg[i] + 1;  // +1 self-loop
    sd[t] = loc;
    __syncthreads();
    for (int o = 128; o > 0; o >>= 1) {
        if (t < o) sd[t] += sd[t + o];
        __syncthreads();
    }
    if (t == 0) {
        part[b] = sd[0];
        __threadfence();
        int old = atomicAdd(ticket, 1);
        lastflag = (old == (int)gridDim.x - 1);
    }
    __syncthreads();
    if (lastflag) {
        __threadfence();
        int v = ((volatile int*)part)[t];
        sd[t] = v;
        __syncthreads();
        for (int o = 1; o < 256; o <<= 1) {
            int u = (t >= o) ? sd[t - o] : 0;
            __syncthreads();
            sd[t] += u;
            __syncthreads();
        }
        part[t] = sd[t] - v;  // exclusive base per block
        if (t == 255) *off_n = sd[255];
    }
}

__global__ __launch_bounds__(256) void k_scan_c(const int* __restrict__ deg,
                                                const int* __restrict__ part,
                                                int* __restrict__ off,
                                                int* __restrict__ cur,
                                                int* __restrict__ srcl,
                                                int* __restrict__ dstl, int n, int CH) {
    __shared__ int sd[256];
    int b = blockIdx.x, t = threadIdx.x;
    int s = b * CH, e = min(n, s + CH);
    int base = part[b];
    for (int c = s; c < e; c += 256) {
        int i = c + t;
        int v = (i < e) ? (deg[i] + 1) : 0;
        sd[t] = v;
        __syncthreads();
        for (int o = 1; o < 256; o <<= 1) {
            int u = (t >= o) ? sd[t - o] : 0;
            __syncthreads();
            sd[t] += u;
            __syncthreads();
        }
        if (i < e) {
            int ex = base + sd[t] - v;
            off[i] = ex;
            cur[i] = ex + 1;   // slot ex holds the self-loop
            srcl[ex] = i;
            dstl[ex] = i;
        }
        base += sd[255];
        __syncthreads();
    }
}

__global__ void k_fill(const int* __restrict__ src, const int* __restrict__ dst,
                       int* cur, int* __restrict__ srcl, int* __restrict__ dstl, int E) {
    int i = blockIdx.x * blockDim.x + threadIdx.x;
    if (i >= E) return;
    int s = src[i], d = dst[i];
    int p = atomicAdd(&cur[d], 1);
    srcl[p] = s;
    dstl[p] = d;
}

// -- GEMM1: 2-term xhi x (W1hi+W1lo), 128x128 tile (blockIdx.y=head), alpha1 fused
#define G1S 40  // LDS row stride in ushort (32 k + 8 pad)
__global__ __launch_bounds__(256) void k_gemm1(const unsigned short* __restrict__ Xhi,
                                               const unsigned short* __restrict__ Whi,
                                               const unsigned short* __restrict__ Wlo,
                                               const float* __restrict__ a1s,
                                               const float* __restrict__ a1d,
                                               unsigned short* __restrict__ h1b,
                                               float* __restrict__ as_,
                                               float* __restrict__ ad_, int M) {
    __shared__ unsigned short sAh[128 * G1S];
    __shared__ unsigned short sBh[128 * G1S], sBl[128 * G1S];
    __shared__ float salS[128][2], salD[128][2];
    int t = threadIdx.x;
    int lane = t & 63, wave = t >> 6;
    int q = lane >> 4, m = lane & 15;
    int row0 = blockIdx.x * 128;
    int head = blockIdx.y;
    int col0 = head * 128;
    int rbase = (wave & 1) * 64, cbase = (wave >> 1) * 64;
    f32x4 acc[4][4];
#pragma unroll
    for (int i = 0; i < 4; ++i)
#pragma unroll
        for (int j = 0; j < 4; ++j) acc[i][j] = (f32x4){0.f, 0.f, 0.f, 0.f};

    for (int kc = 0; kc < 256; kc += 32) {
        // stage A: 128 rows x 32 k (hi only), 512 u16x8 slots
#pragma unroll
        for (int i2 = 0; i2 < 2; ++i2) {
            int slot = t + i2 * 256;
            int r = slot >> 2, kg = slot & 3;
            int row = row0 + r;
            u16x8 vh = {0, 0, 0, 0, 0, 0, 0, 0};
            if (row < M) vh = *(const u16x8*)&Xhi[(size_t)row * 256 + kc + kg * 8];
            *(u16x8*)&sAh[r * G1S + kg * 8] = vh;
        }
        // stage B: 128 cols x 32 k (hi+lo), pre-transposed W [n][k]
#pragma unroll
        for (int i2 = 0; i2 < 2; ++i2) {
            int slot = t + i2 * 256;
            int n = slot >> 2, kg = slot & 3;
            *(u16x8*)&sBh[n * G1S + kg * 8] =
                *(const u16x8*)&Whi[(size_t)(col0 + n) * 256 + kc + kg * 8];
            *(u16x8*)&sBl[n * G1S + kg * 8] =
                *(const u16x8*)&Wlo[(size_t)(col0 + n) * 256 + kc + kg * 8];
        }
        __syncthreads();
        bf16x8 ah[4], bh[4], bl[4];
#pragma unroll
        for (int i = 0; i < 4; ++i)
            ah[i] = *(bf16x8*)&sAh[(rbase + i * 16 + m) * G1S + q * 8];
#pragma unroll
        for (int j = 0; j < 4; ++j) {
            int r = (cbase + j * 16 + m) * G1S + q * 8;
            bh[j] = *(bf16x8*)&sBh[r];
            bl[j] = *(bf16x8*)&sBl[r];
        }
#pragma unroll
        for (int i = 0; i < 4; ++i)
#pragma unroll
            for (int j = 0; j < 4; ++j) {
                acc[i][j] = __builtin_amdgcn_mfma_f32_16x16x32_bf16(ah[i], bl[j], acc[i][j], 0, 0, 0);
                acc[i][j] = __builtin_amdgcn_mfma_f32_16x16x32_bf16(ah[i], bh[j], acc[i][j], 0, 0, 0);
            }
        __syncthreads();
    }
    float sv[4], dv[4];
#pragma unroll
    for (int j = 0; j < 4; ++j) {
        sv[j] = a1s[head * 128 + cbase + j * 16 + m];
        dv[j] = a1d[head * 128 + cbase + j * 16 + m];
    }
#pragma unroll
    for (int i = 0; i < 4; ++i) {
#pragma unroll
        for (int r = 0; r < 4; ++r) {
            int rl = rbase + i * 16 + q * 4 + r;
            int row = row0 + rl;
            float ps = acc[i][0][r] * sv[0] + acc[i][1][r] * sv[1]
                     + acc[i][2][r] * sv[2] + acc[i][3][r] * sv[3];
            float pd = acc[i][0][r] * dv[0] + acc[i][1][r] * dv[1]
                     + acc[i][2][r] * dv[2] + acc[i][3][r] * dv[3];
#pragma unroll
            for (int mask = 1; mask < 16; mask <<= 1) {
                ps += __shfl_xor(ps, mask, 64);
                pd += __shfl_xor(pd, mask, 64);
            }
            if (m == 0) {
                salS[rl][cbase >> 6] = ps;
                salD[rl][cbase >> 6] = pd;
            }
            if (row < M) {
#pragma unroll
                for (int j = 0; j < 4; ++j)
                    h1b[(size_t)row * 256 + col0 + cbase + j * 16 + m] = bf16_rne(acc[i][j][r]);
            }
        }
    }
    __syncthreads();
    if (t < 128) {
        int row = row0 + t;
        if (row < M) {
            as_[row * 2 + head] = salS[t][0] + salS[t][1];
            ad_[row * 2 + head] = salD[t][0] + salD[t][1];
        }
    }
}

// ------- layer-1 per-slot weight precompute (edge-parallel, coalesced) -------
__global__ __launch_bounds__(256) void k_edge1(const int* __restrict__ srcl,
                                               const int* __restrict__ dstl,
                                               const float* __restrict__ as,
                                               const float* __restrict__ ad,
                                               float2* __restrict__ w01, int T) {
    int p = blockIdx.x * blockDim.x + threadIdx.x;
    if (p >= T) return;
    int s = srcl[p], d = dstl[p];
    float2 av = *(const float2*)&as[s * 2];
    float2 dv = *(const float2*)&ad[d * 2];
    float l0 = av.x + dv.x; l0 = l0 >= 0.f ? l0 : NSLOPE * l0;
    float l1 = av.y + dv.y; l1 = l1 >= 0.f ? l1 : NSLOPE * l1;
    w01[p] = make_float2(__expf(l0), __expf(l1));
}

// ------- layer-1 aggregate: round-9 structure, w from precomputed w01 -------
__global__ __launch_bounds__(256) void k_agg1(const unsigned short* __restrict__ h1b,
                                              const float2* __restrict__ w01,
                                              const int* __restrict__ off,
                                              const int* __restrict__ srcl,
                                              const float* __restrict__ b1,
                                              unsigned short* __restrict__ helu_b, int N) {
    int wid = (blockIdx.x * blockDim.x + threadIdx.x) >> 6;
    int lane = threadIdx.x & 63;
    if (wid >= N) return;
    int p0 = off[wid], p1 = off[wid + 1];
    int half = lane >> 5, hl = lane & 31;
    int headL = hl >> 4;
    float acc[8];
#pragma unroll
    for (int c = 0; c < 8; ++c) acc[c] = 0.f;
    float sumw = 0.f;
    for (int base = p0; base < p1; base += 64) {
        int p = base + lane;
        int cnt = min(64, p1 - base);
        int s = 0; float w0 = 0.f, w1 = 0.f;
        if (p < p1) {
            s = srcl[p];
            float2 wv = w01[p];
            w0 = wv.x; w1 = wv.y;
        }
        int pairs = (cnt + 1) >> 1;
        int jj = 0;
        for (; jj + 2 <= pairs; jj += 2) {
            int e0 = 2 * jj + half, e1 = e0 + 2;
            int sa = __shfl(s, e0, 64), sb = __shfl(s, e1, 64);
            float wa0 = __shfl(w0, e0, 64), wa1 = __shfl(w1, e0, 64);
            float wb0 = __shfl(w0, e1, 64), wb1 = __shfl(w1, e1, 64);
            u16x8 hva = *(const u16x8*)&h1b[(size_t)sa * 256 + hl * 8];
            u16x8 hvb = *(const u16x8*)&h1b[(size_t)sb * 256 + hl * 8];
            float wa = headL ? wa1 : wa0;
            float wb = headL ? wb1 : wb0;
            sumw += wa + wb;
#pragma unroll
            for (int c = 0; c < 8; ++c)
                acc[c] += wa * bf16_to_f(hva[c]) + wb * bf16_to_f(hvb[c]);
        }
        for (; jj < pairs; ++jj) {
            int e0 = 2 * jj + half;
            int sa = __shfl(s, e0, 64);
            float wa0 = __shfl(w0, e0, 64), wa1 = __shfl(w1, e0, 64);
            u16x8 hva = *(const u16x8*)&h1b[(size_t)sa * 256 + hl * 8];
            float wa = headL ? wa1 : wa0;
            sumw += wa;
#pragma unroll
            for (int c = 0; c < 8; ++c) acc[c] += wa * bf16_to_f(hva[c]);
        }
    }
#pragma unroll
    for (int c = 0; c < 8; ++c) acc[c] += __shfl_xor(acc[c], 32, 64);
    sumw += __shfl_xor(sumw, 32, 64);
    float inv = 1.0f / sumw;
    int ch = hl * 8 + half * 4;
    float4 bv = *(const float4*)&b1[ch];
    float bb[4] = {bv.x, bv.y, bv.z, bv.w};
    unsigned short o[4];
#pragma unroll
    for (int c = 0; c < 4; ++c) {
        float v = acc[half * 4 + c] * inv + bb[c];
        v = v > 0.f ? v : expm1f(v);
        o[c] = bf16_rne(v);
    }
    *(u16x4*)&helu_b[(size_t)wid * 256 + ch] = *(u16x4*)o;
}

// ---------------- GEMM2: 1-term bf16-A x bf16-B MFMA, alpha2 fused ----------
__global__ __launch_bounds__(256) void k_gemm2(const unsigned short* __restrict__ hb,
                                               const unsigned short* __restrict__ Whi,
                                               const float* __restrict__ a2s,
                                               const float* __restrict__ a2d,
                                               unsigned short* __restrict__ h2b,
                                               float* __restrict__ as_,
                                               float* __restrict__ ad_, int M) {
    __shared__ unsigned short sA[128 * G1S];
    __shared__ unsigned short sBh[64 * G1S];
    int t = threadIdx.x;
    int lane = t & 63, wave = t >> 6;
    int q = lane >> 4, m = lane & 15;
    int row0 = blockIdx.x * 128;
    int rbase = wave * 32;
    f32x4 acc[2][4];
#pragma unroll
    for (int i = 0; i < 2; ++i)
#pragma unroll
        for (int j = 0; j < 4; ++j) acc[i][j] = (f32x4){0.f, 0.f, 0.f, 0.f};

    for (int kc = 0; kc < 256; kc += 32) {
#pragma unroll
        for (int i = 0; i < 2; ++i) {
            int slot = t + i * 256;
            int r = slot >> 2, kg = slot & 3;
            int row = row0 + r;
            u16x8 v = {0, 0, 0, 0, 0, 0, 0, 0};
            if (row < M) v = *(const u16x8*)&hb[(size_t)row * 256 + kc + kg * 8];
            *(u16x8*)&sA[r * G1S + kg * 8] = v;
        }
        {
            int n = t >> 2, kg = t & 3;
            *(u16x8*)&sBh[n * G1S + kg * 8] =
                *(const u16x8*)&Whi[(size_t)n * 256 + kc + kg * 8];
        }
        __syncthreads();
        bf16x8 a[2], bh[4];
#pragma unroll
        for (int i = 0; i < 2; ++i)
            a[i] = *(bf16x8*)&sA[(rbase + i * 16 + m) * G1S + q * 8];
#pragma unroll
        for (int j = 0; j < 4; ++j)
            bh[j] = *(bf16x8*)&sBh[(j * 16 + m) * G1S + q * 8];
#pragma unroll
        for (int i = 0; i < 2; ++i)
#pragma unroll
            for (int j = 0; j < 4; ++j)
                acc[i][j] = __builtin_amdgcn_mfma_f32_16x16x32_bf16(a[i], bh[j], acc[i][j], 0, 0, 0);
        __syncthreads();
    }
    float sv[4], dv[4];
#pragma unroll
    for (int j = 0; j < 4; ++j) {
        sv[j] = a2s[j * 16 + m];
        dv[j] = a2d[j * 16 + m];
    }
#pragma unroll
    for (int i = 0; i < 2; ++i) {
#pragma unroll
        for (int r = 0; r < 4; ++r) {
            int row = row0 + rbase + i * 16 + q * 4 + r;
            float ps = acc[i][0][r] * sv[0] + acc[i][1][r] * sv[1]
                     + acc[i][2][r] * sv[2] + acc[i][3][r] * sv[3];
            float pd = acc[i][0][r] * dv[0] + acc[i][1][r] * dv[1]
                     + acc[i][2][r] * dv[2] + acc[i][3][r] * dv[3];
#pragma unroll
            for (int mask = 1; mask < 16; mask <<= 1) {
                ps += __shfl_xor(ps, mask, 64);
                pd += __shfl_xor(pd, mask, 64);
            }
            if (row < M) {
#pragma unroll
                for (int j = 0; j < 4; ++j)
                    h2b[(size_t)row * 64 + j * 16 + m] = bf16_rne(acc[i][j][r]);
                if (m == 0) { as_[row] = ps; ad_[row] = pd; }
            }
        }
    }
}

// ------- layer-2 per-slot weight precompute -------
__global__ __launch_bounds__(256) void k_edge2(const int* __restrict__ srcl,
                                               const int* __restrict__ dstl,
                                               const float* __restrict__ as,
                                               const float* __restrict__ ad,
                                               float* __restrict__ w2l, int T) {
    int p = blockIdx.x * blockDim.x + threadIdx.x;
    if (p >= T) return;
    int s = srcl[p], d = dstl[p];
    float l = as[s] + ad[d];
    l = l >= 0.f ? l : NSLOPE * l;
    w2l[p] = __expf(l);
}

// ------- layer-2 aggregate: round-9 structure, w from precomputed w2l -------
__global__ __launch_bounds__(256) void k_agg2(const unsigned short* __restrict__ h2b,
                                              const float* __restrict__ w2l,
                                              const int* __restrict__ off,
                                              const int* __restrict__ srcl,
                                              const float* __restrict__ b2,
                                              float* __restrict__ out, int N) {
    int wid = (blockIdx.x * blockDim.x + threadIdx.x) >> 6;
    int lane = threadIdx.x & 63;
    if (wid >= N) return;
    int p0 = off[wid], p1 = off[wid + 1];
    int g = lane >> 4, gl = lane & 15;
    float acc[4];
#pragma unroll
    for (int c = 0; c < 4; ++c) acc[c] = 0.f;
    float sumw = 0.f;
    for (int base = p0; base < p1; base += 64) {
        int p = base + lane;
        int cnt = min(64, p1 - base);
        int s = 0; float w = 0.f;
        if (p < p1) {
            s = srcl[p];
            w = w2l[p];
        }
        int quads = (cnt + 3) >> 2;
        int jj = 0;
        for (; jj + 2 <= quads; jj += 2) {
            int e0 = 4 * jj + g, e1 = e0 + 4;
            int sa = __shfl(s, e0, 64), sb = __shfl(s, e1, 64);
            float wa = __shfl(w, e0, 64), wb = __shfl(w, e1, 64);
            u16x4 hva = *(const u16x4*)&h2b[(size_t)sa * 64 + gl * 4];
            u16x4 hvb = *(const u16x4*)&h2b[(size_t)sb * 64 + gl * 4];
            sumw += wa + wb;
            acc[0] += wa * bf16_to_f(hva.x) + wb * bf16_to_f(hvb.x);
            acc[1] += wa * bf16_to_f(hva.y) + wb * bf16_to_f(hvb.y);
            acc[2] += wa * bf16_to_f(hva.z) + wb * bf16_to_f(hvb.z);
            acc[3] += wa * bf16_to_f(hva.w) + wb * bf16_to_f(hvb.w);
        }
        for (; jj < quads; ++jj) {
            int e0 = 4 * jj + g;
            int sa = __shfl(s, e0, 64);
            float wa = __shfl(w, e0, 64);
            u16x4 hva = *(const u16x4*)&h2b[(size_t)sa * 64 + gl * 4];
            sumw += wa;
            acc[0] += wa * bf16_to_f(hva.x);
            acc[1] += wa * bf16_to_f(hva.y);
            acc[2] += wa * bf16_to_f(hva.z);
            acc[3] += wa * bf16_to_f(hva.w);
        }
    }
#pragma unroll
    for (int c = 0; c < 4; ++c) {
        acc[c] += __shfl_xor(acc[c], 16, 64);
        acc[c] += __shfl_xor(acc[c], 32, 64);
    }
    sumw += __shfl_xor(sumw, 16, 64);
    sumw += __shfl_xor(sumw, 32, 64);
    if (g == 0) {
        float inv = 1.0f / sumw;
        float4 bv = *(const float4*)&b2[gl * 4];
        float4 o;
        o.x = acc[0] * inv + bv.x;
        o.y = acc[1] * inv + bv.y;
        o.z = acc[2] * inv + bv.z;
        o.w = acc[3] * inv + bv.w;
        *(float4*)&out[(size_t)wid * 64 + gl * 4] = o;
    }
}

// ---------------- launch ----------------
extern "C" void kernel_launch(void* const* d_in, const int* in_sizes, int n_in,
                              void* d_out, int out_size, void* d_ws, size_t ws_size,
                              hipStream_t stream) {
    if (n_in < 10) return;
    const float* x   = (const float*)d_in[0];
    const int*   ei  = (const int*)d_in[1];
    const float* W1  = (const float*)d_in[2];
    const float* a1s = (const float*)d_in[3];
    const float* a1d = (const float*)d_in[4];
    const float* b1  = (const float*)d_in[5];
    const float* W2  = (const float*)d_in[6];
    const float* a2s = (const float*)d_in[7];
    const float* a2d = (const float*)d_in[8];
    const float* b2  = (const float*)d_in[9];
    float* out = (float*)d_out;

    const int N = in_sizes[0] / 256;
    const int E = in_sizes[1] / 2;
    const int T = E + N;
    const int* esrc = ei;
    const int* edst = ei + E;

    char* ws = (char*)d_ws;
    size_t o = 0;
    auto alloc = [&](size_t bytes) -> void* {
        void* p = ws + o;
        o = (o + bytes + 255) & ~(size_t)255;
        return p;
    };
    // Xhi (dead after gemm1) aliased with helu_b (written by agg1)
    size_t szX = (size_t)N * 256 * 2;
    char* regionA = (char*)alloc(szX);
    unsigned short* Xhi    = (unsigned short*)regionA;
    unsigned short* helu_b = (unsigned short*)regionA;

    unsigned short* h1b  = (unsigned short*)alloc((size_t)N * 256 * 2);
    unsigned short* W1hi = (unsigned short*)alloc(256 * 256 * 2);
    unsigned short* W1lo = (unsigned short*)alloc(256 * 256 * 2);
    unsigned short* W2hi = (unsigned short*)alloc(64 * 256 * 2);
    unsigned short* h2b  = (unsigned short*)alloc((size_t)N * 64 * 2);
    float* al1s = (float*)alloc((size_t)N * 2 * 4);
    float* al1d = (float*)alloc((size_t)N * 2 * 4);
    float* al2s = (float*)alloc((size_t)N * 4);
    float* al2d = (float*)alloc((size_t)N * 4);
    int* deg  = (int*)alloc((size_t)(N + 64) * 4);  // deg[N] + ticket counter
    int* ticket = deg + N;
    int* off  = (int*)alloc((size_t)(N + 1) * 4);
    int* cur  = (int*)alloc((size_t)N * 4);
    int* part = (int*)alloc(256 * 4);
    int* srcl = (int*)alloc((size_t)T * 4);
    int* dstl = (int*)alloc((size_t)T * 4);
    float2* w01 = (float2*)alloc((size_t)T * 8);
    float* w2l  = (float*)alloc((size_t)T * 4);
    if (o > ws_size) return;

    const int CH = (N + 255) / 256;
    const int total4 = N * 64;
    const int BX = (total4 + 255) / 256;
    const int BH = (E + 255) / 256;
    const int BT = (T + 255) / 256;

    hipMemsetAsync(deg, 0, (size_t)(N + 64) * 4, stream);
    k_prep_all<<<BX + 128 + BH, 256, 0, stream>>>(x, W1, W2, edst, Xhi,
                                                  W1hi, W1lo, W2hi, deg,
                                                  BX, total4, E);
    k_scan_ab<<<256, 256, 0, stream>>>(deg, part, ticket, &off[N], N, CH);
    k_scan_c<<<256, 256, 0, stream>>>(deg, part, off, cur, srcl, dstl, N, CH);
    k_fill<<<(E + 255) / 256, 256, 0, stream>>>(esrc, edst, cur, srcl, dstl, E);

    // layer 1
    dim3 g1((N + 127) / 128, 2);
    k_gemm1<<<g1, 256, 0, stream>>>(Xhi, W1hi, W1lo, a1s, a1d, h1b, al1s, al1d, N);
    k_edge1<<<BT, 256, 0, stream>>>(srcl, dstl, al1s, al1d, w01, T);
    k_agg1<<<(N + 3) / 4, 256, 0, stream>>>(h1b, w01, off, srcl, b1, helu_b, N);

    // layer 2
    k_gemm2<<<(N + 127) / 128, 256, 0, stream>>>(helu_b, W2hi, a2s, a2d,
                                                 h2b, al2s, al2d, N);
    k_edge2<<<BT, 256, 0, stream>>>(srcl, dstl, al2s, al2d, w2l, T);
    k_agg2<<<(N + 3) / 4, 256, 0, stream>>>(h2b, w2l, off, srcl, b2, out, N);
}

// Round 5
// 287.693 us; speedup vs baseline: 1.1495x; 1.0522x over previous
//
#include <hip/hip_runtime.h>
#include <hip/hip_bf16.h>
#include <math.h>

// GAT encoder, round 14.  9 dispatches (round-9 structure):
//  memset | prep_all (x->Xhi, W1->W1hi, W2->W2hi, dst hist) | scan_ab |
//  scan_c | fill | gemm1 (1-term bf16, alpha1 fused) | agg1 | gemm2 | agg2.
// Round-13 post-mortem: edge-parallel weight precompute was net-negative
// (+11us overhead, -1.7us agg1): the weight math sits in agg1's batch phase,
// already latency-hidden.  agg1 ~50us is a local equilibrium -> leave it.
// Round-14 lever: gemm1 was 2-term hi/lo MFMA (26.2 GFLOP, ~44us, the #2
// kernel).  absmax 0.0039 @ threshold 0.01625 = 4x headroom; dropping W1lo
// adds ~1e-3-std error (bf16 W1, rel 2^-9, |W|~1/16, K=256) -> predicted
// absmax ~0.007-0.010, still passing.  Halves gemm1 MFMA + kills sBl LDS.

#define NSLOPE 0.2f

using bf16x8 = __attribute__((ext_vector_type(8))) short;
using f32x4  = __attribute__((ext_vector_type(4))) float;
using u16x8  = __attribute__((ext_vector_type(8))) unsigned short;
using u16x4  = __attribute__((ext_vector_type(4))) unsigned short;

__device__ __forceinline__ unsigned short bf16_rne(float f) {
    unsigned u = __float_as_uint(f);
    return (unsigned short)((u + 0x7FFFu + ((u >> 16) & 1u)) >> 16);
}
__device__ __forceinline__ float bf16_to_f(unsigned short h) {
    return __uint_as_float(((unsigned)h) << 16);
}

// -------- merged prep: x->Xhi | W1->W1hi (transposed) | W2->W2hi | hist -----
__global__ __launch_bounds__(256) void k_prep_all(const float* __restrict__ x,
                                                  const float* __restrict__ W1,
                                                  const float* __restrict__ W2,
                                                  const int* __restrict__ edst,
                                                  unsigned short* __restrict__ Xhi,
                                                  unsigned short* __restrict__ W1hi,
                                                  unsigned short* __restrict__ W2hi,
                                                  int* __restrict__ deg,
                                                  int BX, int total4, int E) {
    int b = blockIdx.x, t = threadIdx.x;
    if (b < BX) {  // x -> bf16 (hi only): 4 floats / thread
        int id = b * 256 + t;
        if (id >= total4) return;
        float4 v = *(const float4*)&x[(size_t)id * 4];
        unsigned short hi[4];
        hi[0] = bf16_rne(v.x); hi[1] = bf16_rne(v.y);
        hi[2] = bf16_rne(v.z); hi[3] = bf16_rne(v.w);
        *(u16x4*)&Xhi[(size_t)id * 4] = *(u16x4*)hi;
    } else if (b < BX + 64) {  // transpose W1 [256,256] -> [n][k], bf16
        int id = (b - BX) * 256 + t;
        int n = id >> 6, kg = id & 63;
        unsigned short hi[4];
#pragma unroll
        for (int c = 0; c < 4; ++c) {
            float w = W1[(kg * 4 + c) * 256 + n];
            hi[c] = bf16_rne(w);
        }
        *(u16x4*)&W1hi[n * 256 + kg * 4] = *(u16x4*)hi;
    } else if (b < BX + 128) {  // transpose W2 [256,64] -> [n][k], bf16
        int id = (b - BX - 64) * 256 + t;
        int n = id >> 8, k = id & 255;
        W2hi[n * 256 + k] = bf16_rne(W2[k * 64 + n]);
    } else {  // dst-degree histogram
        int i = (b - BX - 128) * 256 + t;
        if (i < E) atomicAdd(&deg[edst[i]], 1);
    }
}

// -------- fused scan: per-block sums + last-block scans the 256 partials -----
__global__ __launch_bounds__(256) void k_scan_ab(const int* __restrict__ deg,
                                                 int* __restrict__ part,
                                                 int* __restrict__ ticket,
                                                 int* __restrict__ off_n,
                                                 int n, int CH) {
    __shared__ int sd[256];
    __shared__ int lastflag;
    int b = blockIdx.x, t = threadIdx.x;
    int s = b * CH, e = min(n, s + CH);
    int loc = 0;
    for (int i = s + t; i < e; i += 256) loc += deg[i] + 1;  // +1 self-loop
    sd[t] = loc;
    __syncthreads();
    for (int o = 128; o > 0; o >>= 1) {
        if (t < o) sd[t] += sd[t + o];
        __syncthreads();
    }
    if (t == 0) {
        part[b] = sd[0];
        __threadfence();
        int old = atomicAdd(ticket, 1);
        lastflag = (old == (int)gridDim.x - 1);
    }
    __syncthreads();
    if (lastflag) {
        __threadfence();
        int v = ((volatile int*)part)[t];
        sd[t] = v;
        __syncthreads();
        for (int o = 1; o < 256; o <<= 1) {
            int u = (t >= o) ? sd[t - o] : 0;
            __syncthreads();
            sd[t] += u;
            __syncthreads();
        }
        part[t] = sd[t] - v;  // exclusive base per block
        if (t == 255) *off_n = sd[255];
    }
}

__global__ __launch_bounds__(256) void k_scan_c(const int* __restrict__ deg,
                                                const int* __restrict__ part,
                                                int* __restrict__ off,
                                                int* __restrict__ cur,
                                                int* __restrict__ srcl, int n, int CH) {
    __shared__ int sd[256];
    int b = blockIdx.x, t = threadIdx.x;
    int s = b * CH, e = min(n, s + CH);
    int base = part[b];
    for (int c = s; c < e; c += 256) {
        int i = c + t;
        int v = (i < e) ? (deg[i] + 1) : 0;
        sd[t] = v;
        __syncthreads();
        for (int o = 1; o < 256; o <<= 1) {
            int u = (t >= o) ? sd[t - o] : 0;
            __syncthreads();
            sd[t] += u;
            __syncthreads();
        }
        if (i < e) {
            int ex = base + sd[t] - v;
            off[i] = ex;
            cur[i] = ex + 1;   // slot ex holds the self-loop
            srcl[ex] = i;
        }
        base += sd[255];
        __syncthreads();
    }
}

__global__ void k_fill(const int* __restrict__ src, const int* __restrict__ dst,
                       int* cur, int* __restrict__ srcl, int E) {
    int i = blockIdx.x * blockDim.x + threadIdx.x;
    if (i >= E) return;
    int s = src[i], d = dst[i];
    int p = atomicAdd(&cur[d], 1);
    srcl[p] = s;
}

// -- GEMM1: 1-term xhi x W1hi, 128x128 tile (blockIdx.y=head), alpha1 fused --
#define G1S 40  // LDS row stride in ushort (32 k + 8 pad)
__global__ __launch_bounds__(256) void k_gemm1(const unsigned short* __restrict__ Xhi,
                                               const unsigned short* __restrict__ Whi,
                                               const float* __restrict__ a1s,
                                               const float* __restrict__ a1d,
                                               unsigned short* __restrict__ h1b,
                                               float* __restrict__ as_,
                                               float* __restrict__ ad_, int M) {
    __shared__ unsigned short sAh[128 * G1S];
    __shared__ unsigned short sBh[128 * G1S];
    __shared__ float salS[128][2], salD[128][2];
    int t = threadIdx.x;
    int lane = t & 63, wave = t >> 6;
    int q = lane >> 4, m = lane & 15;
    int row0 = blockIdx.x * 128;
    int head = blockIdx.y;
    int col0 = head * 128;
    int rbase = (wave & 1) * 64, cbase = (wave >> 1) * 64;
    f32x4 acc[4][4];
#pragma unroll
    for (int i = 0; i < 4; ++i)
#pragma unroll
        for (int j = 0; j < 4; ++j) acc[i][j] = (f32x4){0.f, 0.f, 0.f, 0.f};

    for (int kc = 0; kc < 256; kc += 32) {
        // stage A: 128 rows x 32 k, 512 u16x8 slots
#pragma unroll
        for (int i2 = 0; i2 < 2; ++i2) {
            int slot = t + i2 * 256;
            int r = slot >> 2, kg = slot & 3;
            int row = row0 + r;
            u16x8 vh = {0, 0, 0, 0, 0, 0, 0, 0};
            if (row < M) vh = *(const u16x8*)&Xhi[(size_t)row * 256 + kc + kg * 8];
            *(u16x8*)&sAh[r * G1S + kg * 8] = vh;
        }
        // stage B: 128 cols x 32 k, pre-transposed W [n][k]
#pragma unroll
        for (int i2 = 0; i2 < 2; ++i2) {
            int slot = t + i2 * 256;
            int n = slot >> 2, kg = slot & 3;
            *(u16x8*)&sBh[n * G1S + kg * 8] =
                *(const u16x8*)&Whi[(size_t)(col0 + n) * 256 + kc + kg * 8];
        }
        __syncthreads();
        bf16x8 ah[4], bh[4];
#pragma unroll
        for (int i = 0; i < 4; ++i)
            ah[i] = *(bf16x8*)&sAh[(rbase + i * 16 + m) * G1S + q * 8];
#pragma unroll
        for (int j = 0; j < 4; ++j)
            bh[j] = *(bf16x8*)&sBh[(cbase + j * 16 + m) * G1S + q * 8];
#pragma unroll
        for (int i = 0; i < 4; ++i)
#pragma unroll
            for (int j = 0; j < 4; ++j)
                acc[i][j] = __builtin_amdgcn_mfma_f32_16x16x32_bf16(ah[i], bh[j], acc[i][j], 0, 0, 0);
        __syncthreads();
    }
    float sv[4], dv[4];
#pragma unroll
    for (int j = 0; j < 4; ++j) {
        sv[j] = a1s[head * 128 + cbase + j * 16 + m];
        dv[j] = a1d[head * 128 + cbase + j * 16 + m];
    }
#pragma unroll
    for (int i = 0; i < 4; ++i) {
#pragma unroll
        for (int r = 0; r < 4; ++r) {
            int rl = rbase + i * 16 + q * 4 + r;
            int row = row0 + rl;
            float ps = acc[i][0][r] * sv[0] + acc[i][1][r] * sv[1]
                     + acc[i][2][r] * sv[2] + acc[i][3][r] * sv[3];
            float pd = acc[i][0][r] * dv[0] + acc[i][1][r] * dv[1]
                     + acc[i][2][r] * dv[2] + acc[i][3][r] * dv[3];
#pragma unroll
            for (int mask = 1; mask < 16; mask <<= 1) {
                ps += __shfl_xor(ps, mask, 64);
                pd += __shfl_xor(pd, mask, 64);
            }
            if (m == 0) {
                salS[rl][cbase >> 6] = ps;
                salD[rl][cbase >> 6] = pd;
            }
            if (row < M) {
#pragma unroll
                for (int j = 0; j < 4; ++j)
                    h1b[(size_t)row * 256 + col0 + cbase + j * 16 + m] = bf16_rne(acc[i][j][r]);
            }
        }
    }
    __syncthreads();
    if (t < 128) {
        int row = row0 + t;
        if (row < M) {
            as_[row * 2 + head] = salS[t][0] + salS[t][1];
            ad_[row * 2 + head] = salD[t][0] + salD[t][1];
        }
    }
}

// ------- layer-1 aggregate: inline softmax-w, half-wave/edge, 2-in-flight ----
__global__ __launch_bounds__(256) void k_agg1(const unsigned short* __restrict__ h1b,
                                              const float* __restrict__ as,
                                              const float* __restrict__ ad,
                                              const int* __restrict__ off,
                                              const int* __restrict__ srcl,
                                              const float* __restrict__ b1,
                                              unsigned short* __restrict__ helu_b, int N) {
    int wid = (blockIdx.x * blockDim.x + threadIdx.x) >> 6;
    int lane = threadIdx.x & 63;
    if (wid >= N) return;
    int p0 = off[wid], p1 = off[wid + 1];
    float ad0 = ad[wid * 2], ad1 = ad[wid * 2 + 1];
    int half = lane >> 5, hl = lane & 31;
    int headL = hl >> 4;
    float acc[8];
#pragma unroll
    for (int c = 0; c < 8; ++c) acc[c] = 0.f;
    float sumw = 0.f;
    for (int base = p0; base < p1; base += 64) {
        int p = base + lane;
        int cnt = min(64, p1 - base);
        int s = 0; float w0 = 0.f, w1 = 0.f;
        if (p < p1) {
            s = srcl[p];
            float2 av = *(const float2*)&as[s * 2];
            float l0 = av.x + ad0; l0 = l0 >= 0.f ? l0 : NSLOPE * l0;
            float l1 = av.y + ad1; l1 = l1 >= 0.f ? l1 : NSLOPE * l1;
            w0 = __expf(l0); w1 = __expf(l1);
        }
        int pairs = (cnt + 1) >> 1;
        int jj = 0;
        for (; jj + 2 <= pairs; jj += 2) {
            int e0 = 2 * jj + half, e1 = e0 + 2;
            int sa = __shfl(s, e0, 64), sb = __shfl(s, e1, 64);
            float wa0 = __shfl(w0, e0, 64), wa1 = __shfl(w1, e0, 64);
            float wb0 = __shfl(w0, e1, 64), wb1 = __shfl(w1, e1, 64);
            u16x8 hva = *(const u16x8*)&h1b[(size_t)sa * 256 + hl * 8];
            u16x8 hvb = *(const u16x8*)&h1b[(size_t)sb * 256 + hl * 8];
            float wa = headL ? wa1 : wa0;
            float wb = headL ? wb1 : wb0;
            sumw += wa + wb;
#pragma unroll
            for (int c = 0; c < 8; ++c)
                acc[c] += wa * bf16_to_f(hva[c]) + wb * bf16_to_f(hvb[c]);
        }
        for (; jj < pairs; ++jj) {
            int e0 = 2 * jj + half;
            int sa = __shfl(s, e0, 64);
            float wa0 = __shfl(w0, e0, 64), wa1 = __shfl(w1, e0, 64);
            u16x8 hva = *(const u16x8*)&h1b[(size_t)sa * 256 + hl * 8];
            float wa = headL ? wa1 : wa0;
            sumw += wa;
#pragma unroll
            for (int c = 0; c < 8; ++c) acc[c] += wa * bf16_to_f(hva[c]);
        }
    }
#pragma unroll
    for (int c = 0; c < 8; ++c) acc[c] += __shfl_xor(acc[c], 32, 64);
    sumw += __shfl_xor(sumw, 32, 64);
    float inv = 1.0f / sumw;
    int ch = hl * 8 + half * 4;
    float4 bv = *(const float4*)&b1[ch];
    float bb[4] = {bv.x, bv.y, bv.z, bv.w};
    unsigned short o[4];
#pragma unroll
    for (int c = 0; c < 4; ++c) {
        float v = acc[half * 4 + c] * inv + bb[c];
        v = v > 0.f ? v : expm1f(v);
        o[c] = bf16_rne(v);
    }
    *(u16x4*)&helu_b[(size_t)wid * 256 + ch] = *(u16x4*)o;
}

// ---------------- GEMM2: 1-term bf16-A x bf16-B MFMA, alpha2 fused ----------
__global__ __launch_bounds__(256) void k_gemm2(const unsigned short* __restrict__ hb,
                                               const unsigned short* __restrict__ Whi,
                                               const float* __restrict__ a2s,
                                               const float* __restrict__ a2d,
                                               unsigned short* __restrict__ h2b,
                                               float* __restrict__ as_,
                                               float* __restrict__ ad_, int M) {
    __shared__ unsigned short sA[128 * G1S];
    __shared__ unsigned short sBh[64 * G1S];
    int t = threadIdx.x;
    int lane = t & 63, wave = t >> 6;
    int q = lane >> 4, m = lane & 15;
    int row0 = blockIdx.x * 128;
    int rbase = wave * 32;
    f32x4 acc[2][4];
#pragma unroll
    for (int i = 0; i < 2; ++i)
#pragma unroll
        for (int j = 0; j < 4; ++j) acc[i][j] = (f32x4){0.f, 0.f, 0.f, 0.f};

    for (int kc = 0; kc < 256; kc += 32) {
#pragma unroll
        for (int i = 0; i < 2; ++i) {
            int slot = t + i * 256;
            int r = slot >> 2, kg = slot & 3;
            int row = row0 + r;
            u16x8 v = {0, 0, 0, 0, 0, 0, 0, 0};
            if (row < M) v = *(const u16x8*)&hb[(size_t)row * 256 + kc + kg * 8];
            *(u16x8*)&sA[r * G1S + kg * 8] = v;
        }
        {
            int n = t >> 2, kg = t & 3;
            *(u16x8*)&sBh[n * G1S + kg * 8] =
                *(const u16x8*)&Whi[(size_t)n * 256 + kc + kg * 8];
        }
        __syncthreads();
        bf16x8 a[2], bh[4];
#pragma unroll
        for (int i = 0; i < 2; ++i)
            a[i] = *(bf16x8*)&sA[(rbase + i * 16 + m) * G1S + q * 8];
#pragma unroll
        for (int j = 0; j < 4; ++j)
            bh[j] = *(bf16x8*)&sBh[(j * 16 + m) * G1S + q * 8];
#pragma unroll
        for (int i = 0; i < 2; ++i)
#pragma unroll
            for (int j = 0; j < 4; ++j)
                acc[i][j] = __builtin_amdgcn_mfma_f32_16x16x32_bf16(a[i], bh[j], acc[i][j], 0, 0, 0);
        __syncthreads();
    }
    float sv[4], dv[4];
#pragma unroll
    for (int j = 0; j < 4; ++j) {
        sv[j] = a2s[j * 16 + m];
        dv[j] = a2d[j * 16 + m];
    }
#pragma unroll
    for (int i = 0; i < 2; ++i) {
#pragma unroll
        for (int r = 0; r < 4; ++r) {
            int row = row0 + rbase + i * 16 + q * 4 + r;
            float ps = acc[i][0][r] * sv[0] + acc[i][1][r] * sv[1]
                     + acc[i][2][r] * sv[2] + acc[i][3][r] * sv[3];
            float pd = acc[i][0][r] * dv[0] + acc[i][1][r] * dv[1]
                     + acc[i][2][r] * dv[2] + acc[i][3][r] * dv[3];
#pragma unroll
            for (int mask = 1; mask < 16; mask <<= 1) {
                ps += __shfl_xor(ps, mask, 64);
                pd += __shfl_xor(pd, mask, 64);
            }
            if (row < M) {
#pragma unroll
                for (int j = 0; j < 4; ++j)
                    h2b[(size_t)row * 64 + j * 16 + m] = bf16_rne(acc[i][j][r]);
                if (m == 0) { as_[row] = ps; ad_[row] = pd; }
            }
        }
    }
}

// ------- layer-2 aggregate: inline w, quarter-wave/edge, 2-in-flight --------
__global__ __launch_bounds__(256) void k_agg2(const unsigned short* __restrict__ h2b,
                                              const float* __restrict__ as,
                                              const float* __restrict__ ad,
                                              const int* __restrict__ off,
                                              const int* __restrict__ srcl,
                                              const float* __restrict__ b2,
                                              float* __restrict__ out, int N) {
    int wid = (blockIdx.x * blockDim.x + threadIdx.x) >> 6;
    int lane = threadIdx.x & 63;
    if (wid >= N) return;
    int p0 = off[wid], p1 = off[wid + 1];
    float adw = ad[wid];
    int g = lane >> 4, gl = lane & 15;
    float acc[4];
#pragma unroll
    for (int c = 0; c < 4; ++c) acc[c] = 0.f;
    float sumw = 0.f;
    for (int base = p0; base < p1; base += 64) {
        int p = base + lane;
        int cnt = min(64, p1 - base);
        int s = 0; float w = 0.f;
        if (p < p1) {
            s = srcl[p];
            float l = as[s] + adw;
            l = l >= 0.f ? l : NSLOPE * l;
            w = __expf(l);
        }
        int quads = (cnt + 3) >> 2;
        int jj = 0;
        for (; jj + 2 <= quads; jj += 2) {
            int e0 = 4 * jj + g, e1 = e0 + 4;
            int sa = __shfl(s, e0, 64), sb = __shfl(s, e1, 64);
            float wa = __shfl(w, e0, 64), wb = __shfl(w, e1, 64);
            u16x4 hva = *(const u16x4*)&h2b[(size_t)sa * 64 + gl * 4];
            u16x4 hvb = *(const u16x4*)&h2b[(size_t)sb * 64 + gl * 4];
            sumw += wa + wb;
            acc[0] += wa * bf16_to_f(hva.x) + wb * bf16_to_f(hvb.x);
            acc[1] += wa * bf16_to_f(hva.y) + wb * bf16_to_f(hvb.y);
            acc[2] += wa * bf16_to_f(hva.z) + wb * bf16_to_f(hvb.z);
            acc[3] += wa * bf16_to_f(hva.w) + wb * bf16_to_f(hvb.w);
        }
        for (; jj < quads; ++jj) {
            int e0 = 4 * jj + g;
            int sa = __shfl(s, e0, 64);
            float wa = __shfl(w, e0, 64);
            u16x4 hva = *(const u16x4*)&h2b[(size_t)sa * 64 + gl * 4];
            sumw += wa;
            acc[0] += wa * bf16_to_f(hva.x);
            acc[1] += wa * bf16_to_f(hva.y);
            acc[2] += wa * bf16_to_f(hva.z);
            acc[3] += wa * bf16_to_f(hva.w);
        }
    }
#pragma unroll
    for (int c = 0; c < 4; ++c) {
        acc[c] += __shfl_xor(acc[c], 16, 64);
        acc[c] += __shfl_xor(acc[c], 32, 64);
    }
    sumw += __shfl_xor(sumw, 16, 64);
    sumw += __shfl_xor(sumw, 32, 64);
    if (g == 0) {
        float inv = 1.0f / sumw;
        float4 bv = *(const float4*)&b2[gl * 4];
        float4 o;
        o.x = acc[0] * inv + bv.x;
        o.y = acc[1] * inv + bv.y;
        o.z = acc[2] * inv + bv.z;
        o.w = acc[3] * inv + bv.w;
        *(float4*)&out[(size_t)wid * 64 + gl * 4] = o;
    }
}

// ---------------- launch ----------------
extern "C" void kernel_launch(void* const* d_in, const int* in_sizes, int n_in,
                              void* d_out, int out_size, void* d_ws, size_t ws_size,
                              hipStream_t stream) {
    if (n_in < 10) return;
    const float* x   = (const float*)d_in[0];
    const int*   ei  = (const int*)d_in[1];
    const float* W1  = (const float*)d_in[2];
    const float* a1s = (const float*)d_in[3];
    const float* a1d = (const float*)d_in[4];
    const float* b1  = (const float*)d_in[5];
    const float* W2  = (const float*)d_in[6];
    const float* a2s = (const float*)d_in[7];
    const float* a2d = (const float*)d_in[8];
    const float* b2  = (const float*)d_in[9];
    float* out = (float*)d_out;

    const int N = in_sizes[0] / 256;
    const int E = in_sizes[1] / 2;
    const int T = E + N;
    const int* esrc = ei;
    const int* edst = ei + E;

    char* ws = (char*)d_ws;
    size_t o = 0;
    auto alloc = [&](size_t bytes) -> void* {
        void* p = ws + o;
        o = (o + bytes + 255) & ~(size_t)255;
        return p;
    };
    // Xhi (dead after gemm1) aliased with helu_b (written by agg1)
    size_t szX = (size_t)N * 256 * 2;
    char* regionA = (char*)alloc(szX);
    unsigned short* Xhi    = (unsigned short*)regionA;
    unsigned short* helu_b = (unsigned short*)regionA;

    unsigned short* h1b  = (unsigned short*)alloc((size_t)N * 256 * 2);
    unsigned short* W1hi = (unsigned short*)alloc(256 * 256 * 2);
    unsigned short* W2hi = (unsigned short*)alloc(64 * 256 * 2);
    unsigned short* h2b  = (unsigned short*)alloc((size_t)N * 64 * 2);
    float* al1s = (float*)alloc((size_t)N * 2 * 4);
    float* al1d = (float*)alloc((size_t)N * 2 * 4);
    float* al2s = (float*)alloc((size_t)N * 4);
    float* al2d = (float*)alloc((size_t)N * 4);
    int* deg  = (int*)alloc((size_t)(N + 64) * 4);  // deg[N] + ticket counter
    int* ticket = deg + N;
    int* off  = (int*)alloc((size_t)(N + 1) * 4);
    int* cur  = (int*)alloc((size_t)N * 4);
    int* part = (int*)alloc(256 * 4);
    int* srcl = (int*)alloc((size_t)T * 4);
    if (o > ws_size) return;

    const int CH = (N + 255) / 256;
    const int total4 = N * 64;
    const int BX = (total4 + 255) / 256;
    const int BH = (E + 255) / 256;

    hipMemsetAsync(deg, 0, (size_t)(N + 64) * 4, stream);
    k_prep_all<<<BX + 128 + BH, 256, 0, stream>>>(x, W1, W2, edst, Xhi,
                                                  W1hi, W2hi, deg,
                                                  BX, total4, E);
    k_scan_ab<<<256, 256, 0, stream>>>(deg, part, ticket, &off[N], N, CH);
    k_scan_c<<<256, 256, 0, stream>>>(deg, part, off, cur, srcl, N, CH);
    k_fill<<<(E + 255) / 256, 256, 0, stream>>>(esrc, edst, cur, srcl, E);

    // layer 1
    dim3 g1((N + 127) / 128, 2);
    k_gemm1<<<g1, 256, 0, stream>>>(Xhi, W1hi, a1s, a1d, h1b, al1s, al1d, N);
    k_agg1<<<(N + 3) / 4, 256, 0, stream>>>(h1b, al1s, al1d, off, srcl, b1, helu_b, N);

    // layer 2
    k_gemm2<<<(N + 127) / 128, 256, 0, stream>>>(helu_b, W2hi, a2s, a2d,
                                                 h2b, al2s, al2d, N);
    k_agg2<<<(N + 3) / 4, 256, 0, stream>>>(h2b, al2s, al2d, off, srcl, b2, out, N);
}